// Round 8
// baseline (61.613 us; speedup 1.0000x reference)
//
#include <hip/hip_runtime.h>
#include <hip/hip_fp16.h>
#include <stdint.h>

#define BATCH   1024
#define IDIM    4096
#define NLUTS   16384

// ---- main kernel geometry ----
#define TPB     512
#define NT      2                  // n's per thread
#define NPB     (TPB * NT)         // 1024
#define NBLK_N  (NLUTS / NPB)      // 16
#define BT      4                  // batch rows per tile (fp16 -> ds_read_b64 gather)
#define ROWS    BT                 // single tile per block
#define NBLK_B  (BATCH / ROWS)     // 256
#define GRID    (NBLK_N * NBLK_B)  // 4096 blocks = 16 queued/CU, ~4 resident

// ---------------- coefficient pre-kernel ----------------
// a[n][mask]: monomial coefficients of the multilinear form, from
// s = sigmoid(w - wc) reversed + 4-level butterfly (p0,p1)->(p1,p0-p1).
__global__ __launch_bounds__(256, 4)
void coeff_kernel(const float* __restrict__ w,
                  const float* __restrict__ wc,
                  float* __restrict__ cf)
{
    int n = blockIdx.x * 256 + threadIdx.x;   // grid = 64 x 256
    float p[16];
#pragma unroll
    for (int k = 0; k < 4; ++k) {
        float4 wv = *reinterpret_cast<const float4*>(w  + (size_t)n * 16 + 4 * k);
        float4 cv = *reinterpret_cast<const float4*>(wc + (size_t)n * 16 + 4 * k);
        p[15 - (4 * k + 0)] = 1.f / (1.f + __expf(cv.x - wv.x));
        p[15 - (4 * k + 1)] = 1.f / (1.f + __expf(cv.y - wv.y));
        p[15 - (4 * k + 2)] = 1.f / (1.f + __expf(cv.z - wv.z));
        p[15 - (4 * k + 3)] = 1.f / (1.f + __expf(cv.w - wv.w));
    }
#pragma unroll
    for (int s = 8; s >= 1; s >>= 1) {
#pragma unroll
        for (int m = 0; m < 16; ++m) {
            if ((m & s) == 0) { float t0 = p[m]; p[m] = p[m + s]; p[m + s] = t0 - p[m + s]; }
        }
    }
#pragma unroll
    for (int k = 0; k < 4; ++k) {
        float4 o; o.x = p[4*k]; o.y = p[4*k+1]; o.z = p[4*k+2]; o.w = p[4*k+3];
        *reinterpret_cast<float4*>(cf + (size_t)n * 16 + 4 * k) = o;
    }
}

// ---------------- main kernel ----------------
// Deep-queue single-tile blocks: 1 barrier per block, 16 blocks queued per
// CU so the scheduler refills as blocks finish — inter-block TLP hides the
// staging latency that intra-block barriers serialized in R1-R7.
// launch_bounds(512,4): proven VGPR=40/no-spill recipe (R6/R7).
__global__ __launch_bounds__(TPB, 4)
void lut_main(const float* __restrict__ x,
              const float* __restrict__ cf,
              const int*   __restrict__ indices,
              float* __restrict__ out)
{
    // transposed fp16 tile: xt[col*4 + r] = x[b0+r][col]. 32 KB.
    __shared__ __half xt[IDIM * BT];

    // XCD swizzle: per XCD, n_blk varies fastest -> the 16 n-blocks sharing a
    // b-range run back-to-back on one XCD; x rows + full cf stay L2-resident.
    int id    = blockIdx.x;
    int xcd   = id & 7;
    int k     = id >> 3;                 // 0..511
    int n_blk = k & (NBLK_N - 1);        // 0..15, fastest
    int b_blk = (k >> 4) * 8 + xcd;      // 0..255, bijective
    int t     = threadIdx.x;
    int n0    = n_blk * NPB + t * NT;
    int b0    = b_blk * ROWS;

    // ---- stage tile: thread owns col pairs p = t + 512*h, h=0..3 ----
    // (h-loop outer keeps live floats low -> VGPR=40, the R6/R7 result)
    {
        const float* xb = x + (size_t)b0 * IDIM;
#pragma unroll
        for (int h = 0; h < 4; ++h) {
            int p = h * TPB + t;
            int c = 2 * p;
            float2 r0 = *reinterpret_cast<const float2*>(xb + 0 * IDIM + c);
            float2 r1 = *reinterpret_cast<const float2*>(xb + 1 * IDIM + c);
            float2 r2 = *reinterpret_cast<const float2*>(xb + 2 * IDIM + c);
            float2 r3 = *reinterpret_cast<const float2*>(xb + 3 * IDIM + c);
            __half2 c0a = __floats2half2_rn(r0.x, r1.x);   // col c   rows 0,1
            __half2 c0b = __floats2half2_rn(r2.x, r3.x);   // col c   rows 2,3
            __half2 c1a = __floats2half2_rn(r0.y, r1.y);   // col c+1 rows 0,1
            __half2 c1b = __floats2half2_rn(r2.y, r3.y);   // col c+1 rows 2,3
            uint4 v;
            v.x = *reinterpret_cast<uint32_t*>(&c0a);
            v.y = *reinterpret_cast<uint32_t*>(&c0b);
            v.z = *reinterpret_cast<uint32_t*>(&c1a);
            v.w = *reinterpret_cast<uint32_t*>(&c1b);
            *reinterpret_cast<uint4*>(&xt[(size_t)c * 4]) = v;
        }
    }

    // prologue loads AFTER issuing stage (their latency hides under staging)
    // per-thread LUT indices -> LDS byte offsets (ix*8B per column)
    uint32_t off[NT][4];
#pragma unroll
    for (int i = 0; i < 4; ++i) {
        int2 v = *reinterpret_cast<const int2*>(indices + i * NLUTS + n0);
        off[0][i] = (uint32_t)v.x * 8u;
        off[1][i] = (uint32_t)v.y * 8u;
    }

    // per-thread monomial coefficients (precomputed, 1 MiB, L2-hot)
    float a[NT][16];
#pragma unroll
    for (int q = 0; q < NT; ++q) {
#pragma unroll
        for (int kk = 0; kk < 4; ++kk) {
            float4 v = *reinterpret_cast<const float4*>(cf + (size_t)(n0 + q) * 16 + 4 * kk);
            a[q][4*kk] = v.x; a[q][4*kk+1] = v.y; a[q][4*kk+2] = v.z; a[q][4*kk+3] = v.w;
        }
    }

    __syncthreads();                   // tile visible to all waves

    const char* xt_bytes = reinterpret_cast<const char*>(xt);

    // ---- compute: per q, 4 x ds_read_b64 gathers (4 rows each) ----
    float res[NT][BT];
#pragma unroll
    for (int q = 0; q < NT; ++q) {
        uint2 gld[4];
#pragma unroll
        for (int i = 0; i < 4; ++i)
            gld[i] = *reinterpret_cast<const uint2*>(xt_bytes + off[q][i]);

        // convert each gathered column ONCE: c[i][r] = x[row r][col i]
        float c[4][4];
#pragma unroll
        for (int i = 0; i < 4; ++i) {
            __half2 h01 = *reinterpret_cast<__half2*>(&gld[i].x);
            __half2 h23 = *reinterpret_cast<__half2*>(&gld[i].y);
            float2 f01 = __half22float2(h01);
            float2 f23 = __half22float2(h23);
            c[i][0] = f01.x; c[i][1] = f01.y; c[i][2] = f23.x; c[i][3] = f23.y;
        }
#pragma unroll
        for (int r = 0; r < BT; ++r) {
            float v0 = c[0][r], v1 = c[1][r], v2 = c[2][r], v3 = c[3][r];
            float h0 = fmaf(v3, a[q][1],  a[q][0]);
            float h1 = fmaf(v3, a[q][3],  a[q][2]);
            float h2 = fmaf(v3, a[q][5],  a[q][4]);
            float h3 = fmaf(v3, a[q][7],  a[q][6]);
            float h4 = fmaf(v3, a[q][9],  a[q][8]);
            float h5 = fmaf(v3, a[q][11], a[q][10]);
            float h6 = fmaf(v3, a[q][13], a[q][12]);
            float h7 = fmaf(v3, a[q][15], a[q][14]);
            float g0 = fmaf(v2, h1, h0);
            float g1 = fmaf(v2, h3, h2);
            float g2 = fmaf(v2, h5, h4);
            float g3 = fmaf(v2, h7, h6);
            float f0 = fmaf(v1, g1, g0);
            float f1 = fmaf(v1, g3, g2);
            res[q][r] = fmaf(v0, f1, f0);
        }
    }

    // coalesced float2 stores: 4 rows x (2 consecutive n per thread)
#pragma unroll
    for (int r = 0; r < BT; ++r) {
        float2 o; o.x = res[0][r]; o.y = res[1][r];
        *reinterpret_cast<float2*>(out + (size_t)(b0 + r) * NLUTS + n0) = o;
    }
}

// ---------------- fallback (round-1 fused kernel, used only if ws too small) ----------------
#define F_TPB   256
#define F_NT    4
#define F_NPB   (F_TPB * F_NT)
#define F_NBLKN (NLUTS / F_NPB)
#define F_BTILE 16
#define F_GRID  (F_NBLKN * (BATCH / F_BTILE))

__global__ __launch_bounds__(F_TPB, 4)
void lut_fused(const float* __restrict__ x, const float* __restrict__ w,
               const float* __restrict__ wcomp, const int* __restrict__ indices,
               float* __restrict__ out)
{
    __shared__ float xsf[2][IDIM];
    int id = blockIdx.x;
    int swz = (id & 7) * (F_GRID / 8) + (id >> 3);
    int b_blk = swz / F_NBLKN, n_blk = swz % F_NBLKN;
    int t = threadIdx.x;
    int n0 = n_blk * F_NPB + t * F_NT;
    int b0 = b_blk * F_BTILE;
    int ix[F_NT][4];
#pragma unroll
    for (int i = 0; i < 4; ++i) {
        int4 v = *reinterpret_cast<const int4*>(indices + i * NLUTS + n0);
        ix[0][i] = v.x; ix[1][i] = v.y; ix[2][i] = v.z; ix[3][i] = v.w;
    }
    float a[F_NT][16];
#pragma unroll
    for (int q = 0; q < F_NT; ++q) {
        int n = n0 + q; float p[16];
#pragma unroll
        for (int k = 0; k < 4; ++k) {
            float4 wv = *reinterpret_cast<const float4*>(w     + (size_t)n * 16 + k * 4);
            float4 cv = *reinterpret_cast<const float4*>(wcomp + (size_t)n * 16 + k * 4);
            p[15-(4*k+0)] = 1.f/(1.f+__expf(cv.x-wv.x));
            p[15-(4*k+1)] = 1.f/(1.f+__expf(cv.y-wv.y));
            p[15-(4*k+2)] = 1.f/(1.f+__expf(cv.z-wv.z));
            p[15-(4*k+3)] = 1.f/(1.f+__expf(cv.w-wv.w));
        }
#pragma unroll
        for (int s = 8; s >= 1; s >>= 1)
#pragma unroll
            for (int m = 0; m < 16; ++m)
                if ((m & s) == 0) { float t0 = p[m]; p[m] = p[m+s]; p[m+s] = t0 - p[m+s]; }
#pragma unroll
        for (int m = 0; m < 16; ++m) a[q][m] = p[m];
    }
    {
        const float* xrow = x + (size_t)b0 * IDIM;
#pragma unroll
        for (int k = 0; k < 4; ++k)
            *reinterpret_cast<float4*>(&xsf[0][(k*F_TPB+t)*4]) =
                *reinterpret_cast<const float4*>(xrow + (k*F_TPB+t)*4);
    }
    __syncthreads();
    for (int bi = 0; bi < F_BTILE; ++bi) {
        int cur = bi & 1; bool more = (bi + 1 < F_BTILE);
        float4 r[4];
        if (more) {
            const float* xrow = x + (size_t)(b0+bi+1) * IDIM;
#pragma unroll
            for (int k = 0; k < 4; ++k)
                r[k] = *reinterpret_cast<const float4*>(xrow + (k*F_TPB+t)*4);
        }
        float res[F_NT];
#pragma unroll
        for (int q = 0; q < F_NT; ++q) {
            float v0 = xsf[cur][ix[q][0]], v1 = xsf[cur][ix[q][1]];
            float v2 = xsf[cur][ix[q][2]], v3 = xsf[cur][ix[q][3]];
            float h0 = fmaf(v3,a[q][1],a[q][0]),  h1 = fmaf(v3,a[q][3],a[q][2]);
            float h2 = fmaf(v3,a[q][5],a[q][4]),  h3 = fmaf(v3,a[q][7],a[q][6]);
            float h4 = fmaf(v3,a[q][9],a[q][8]),  h5 = fmaf(v3,a[q][11],a[q][10]);
            float h6 = fmaf(v3,a[q][13],a[q][12]),h7 = fmaf(v3,a[q][15],a[q][14]);
            float g0 = fmaf(v2,h1,h0), g1 = fmaf(v2,h3,h2);
            float g2 = fmaf(v2,h5,h4), g3 = fmaf(v2,h7,h6);
            res[q] = fmaf(v0, fmaf(v1,g3,g2), fmaf(v1,g1,g0));
        }
        float4 o; o.x=res[0]; o.y=res[1]; o.z=res[2]; o.w=res[3];
        *reinterpret_cast<float4*>(out + (size_t)(b0+bi)*NLUTS + n0) = o;
        if (more) {
            int nxt = cur ^ 1;
#pragma unroll
            for (int k = 0; k < 4; ++k)
                *reinterpret_cast<float4*>(&xsf[nxt][(k*F_TPB+t)*4]) = r[k];
        }
        __syncthreads();
    }
}

extern "C" void kernel_launch(void* const* d_in, const int* in_sizes, int n_in,
                              void* d_out, int out_size, void* d_ws, size_t ws_size,
                              hipStream_t stream) {
    const float* x   = (const float*)d_in[0];
    const float* w   = (const float*)d_in[1];
    const float* wc  = (const float*)d_in[2];
    const int*   idx = (const int*)d_in[3];
    float*       out = (float*)d_out;

    if (ws_size >= (size_t)NLUTS * 16 * sizeof(float)) {
        float* cf = (float*)d_ws;
        coeff_kernel<<<dim3(NLUTS / 256), dim3(256), 0, stream>>>(w, wc, cf);
        lut_main<<<dim3(GRID), dim3(TPB), 0, stream>>>(x, cf, idx, out);
    } else {
        lut_fused<<<dim3(F_GRID), dim3(F_TPB), 0, stream>>>(x, w, wc, idx, out);
    }
}

// Round 9
// 52.697 us; speedup vs baseline: 1.1692x; 1.1692x over previous
//
#include <hip/hip_runtime.h>
#include <hip/hip_fp16.h>
#include <stdint.h>

#define BATCH   1024
#define IDIM    4096
#define NLUTS   16384

// ---- main kernel geometry ----
#define TPB     512
#define NT      2                   // n's per thread per chunk
#define BT      4                   // batch rows per block (fp16 tile, b64 gather)
#define NHALF   (NLUTS / 2)         // 8192: n-range swept by one block
#define CHUNKS  (NHALF / (TPB*NT))  // 8 chunks, barrier-free streaming loop
#define GRID    ((BATCH / BT) * 2)  // 512 blocks = 2 per CU

// ---------------- coefficient pre-kernel ----------------
// a[n][mask]: monomial coefficients of the multilinear form, from
// s = sigmoid(w - wc) reversed + 4-level butterfly (p0,p1)->(p1,p0-p1).
__global__ __launch_bounds__(256, 4)
void coeff_kernel(const float* __restrict__ w,
                  const float* __restrict__ wc,
                  float* __restrict__ cf)
{
    int n = blockIdx.x * 256 + threadIdx.x;   // grid = 64 x 256
    float p[16];
#pragma unroll
    for (int k = 0; k < 4; ++k) {
        float4 wv = *reinterpret_cast<const float4*>(w  + (size_t)n * 16 + 4 * k);
        float4 cv = *reinterpret_cast<const float4*>(wc + (size_t)n * 16 + 4 * k);
        p[15 - (4 * k + 0)] = 1.f / (1.f + __expf(cv.x - wv.x));
        p[15 - (4 * k + 1)] = 1.f / (1.f + __expf(cv.y - wv.y));
        p[15 - (4 * k + 2)] = 1.f / (1.f + __expf(cv.z - wv.z));
        p[15 - (4 * k + 3)] = 1.f / (1.f + __expf(cv.w - wv.w));
    }
#pragma unroll
    for (int s = 8; s >= 1; s >>= 1) {
#pragma unroll
        for (int m = 0; m < 16; ++m) {
            if ((m & s) == 0) { float t0 = p[m]; p[m] = p[m + s]; p[m + s] = t0 - p[m + s]; }
        }
    }
#pragma unroll
    for (int k = 0; k < 4; ++k) {
        float4 o; o.x = p[4*k]; o.y = p[4*k+1]; o.z = p[4*k+2]; o.w = p[4*k+3];
        *reinterpret_cast<float4*>(cf + (size_t)n * 16 + 4 * k) = o;
    }
}

// ---------------- main kernel ----------------
// ONE stage + ONE barrier per block, then a long barrier-free sweep over
// 8192 n's: idx/cf streaming loads, LDS gathers, Horner FMAs and stores all
// overlap across 16 waves/CU — no lockstep stalls (the R1-R8 limiter).
__global__ __launch_bounds__(TPB, 4)
void lut_main(const float* __restrict__ x,
              const float* __restrict__ cf,
              const int*   __restrict__ indices,
              float* __restrict__ out)
{
    // transposed fp16 tile: xt[col*4 + r] = x[b0+r][col]. 32 KB.
    __shared__ __half xt[IDIM * BT];

    // XCD swizzle: the two n-half blocks of one b-group sit adjacent on the
    // same XCD (share the staged x rows via its L2); b-groups stride by 8.
    int id   = blockIdx.x;
    int xcd  = id & 7;
    int k    = id >> 3;                 // 0..63
    int half = k & 1;
    int bgrp = (k >> 1) * 8 + xcd;      // 0..255, bijective
    int t    = threadIdx.x;
    int b0   = bgrp * BT;
    int nbase = half * NHALF;

    // ---- stage tile: thread owns col pairs p = t + 512*h, h=0..3 ----
    // (proven VGPR=36/no-spill pattern from R8)
    {
        const float* xb = x + (size_t)b0 * IDIM;
#pragma unroll
        for (int h = 0; h < 4; ++h) {
            int p = h * TPB + t;
            int c = 2 * p;
            float2 r0 = *reinterpret_cast<const float2*>(xb + 0 * IDIM + c);
            float2 r1 = *reinterpret_cast<const float2*>(xb + 1 * IDIM + c);
            float2 r2 = *reinterpret_cast<const float2*>(xb + 2 * IDIM + c);
            float2 r3 = *reinterpret_cast<const float2*>(xb + 3 * IDIM + c);
            __half2 c0a = __floats2half2_rn(r0.x, r1.x);   // col c   rows 0,1
            __half2 c0b = __floats2half2_rn(r2.x, r3.x);   // col c   rows 2,3
            __half2 c1a = __floats2half2_rn(r0.y, r1.y);   // col c+1 rows 0,1
            __half2 c1b = __floats2half2_rn(r2.y, r3.y);   // col c+1 rows 2,3
            uint4 v;
            v.x = *reinterpret_cast<uint32_t*>(&c0a);
            v.y = *reinterpret_cast<uint32_t*>(&c0b);
            v.z = *reinterpret_cast<uint32_t*>(&c1a);
            v.w = *reinterpret_cast<uint32_t*>(&c1b);
            *reinterpret_cast<uint4*>(&xt[(size_t)c * 4]) = v;
        }
    }
    __syncthreads();                   // the ONLY barrier in the kernel

    const char* xt_bytes = reinterpret_cast<const char*>(xt);

    // ---- barrier-free sweep: 8 chunks x (2 n per thread) = 8192 n ----
#pragma unroll 1
    for (int c = 0; c < CHUNKS; ++c) {
        int n0 = nbase + c * (TPB * NT) + t * NT;

        // per-chunk LUT indices -> LDS byte offsets
        uint32_t off[NT][4];
#pragma unroll
        for (int i = 0; i < 4; ++i) {
            int2 v = *reinterpret_cast<const int2*>(indices + i * NLUTS + n0);
            off[0][i] = (uint32_t)v.x * 8u;
            off[1][i] = (uint32_t)v.y * 8u;
        }

        // per-chunk coefficients (independent of gathers -> overlaps them)
        float a[NT][16];
#pragma unroll
        for (int q = 0; q < NT; ++q) {
#pragma unroll
            for (int kk = 0; kk < 4; ++kk) {
                float4 v = *reinterpret_cast<const float4*>(cf + (size_t)(n0 + q) * 16 + 4 * kk);
                a[q][4*kk] = v.x; a[q][4*kk+1] = v.y; a[q][4*kk+2] = v.z; a[q][4*kk+3] = v.w;
            }
        }

        float res[NT][BT];
#pragma unroll
        for (int q = 0; q < NT; ++q) {
            uint2 gld[4];
#pragma unroll
            for (int i = 0; i < 4; ++i)
                gld[i] = *reinterpret_cast<const uint2*>(xt_bytes + off[q][i]);

            // convert each gathered column ONCE: cc[i][r] = x[row r][col i]
            float cc[4][4];
#pragma unroll
            for (int i = 0; i < 4; ++i) {
                __half2 h01 = *reinterpret_cast<__half2*>(&gld[i].x);
                __half2 h23 = *reinterpret_cast<__half2*>(&gld[i].y);
                float2 f01 = __half22float2(h01);
                float2 f23 = __half22float2(h23);
                cc[i][0] = f01.x; cc[i][1] = f01.y; cc[i][2] = f23.x; cc[i][3] = f23.y;
            }
#pragma unroll
            for (int r = 0; r < BT; ++r) {
                float v0 = cc[0][r], v1 = cc[1][r], v2 = cc[2][r], v3 = cc[3][r];
                float h0 = fmaf(v3, a[q][1],  a[q][0]);
                float h1 = fmaf(v3, a[q][3],  a[q][2]);
                float h2 = fmaf(v3, a[q][5],  a[q][4]);
                float h3 = fmaf(v3, a[q][7],  a[q][6]);
                float h4 = fmaf(v3, a[q][9],  a[q][8]);
                float h5 = fmaf(v3, a[q][11], a[q][10]);
                float h6 = fmaf(v3, a[q][13], a[q][12]);
                float h7 = fmaf(v3, a[q][15], a[q][14]);
                float g0 = fmaf(v2, h1, h0);
                float g1 = fmaf(v2, h3, h2);
                float g2 = fmaf(v2, h5, h4);
                float g3 = fmaf(v2, h7, h6);
                float f0 = fmaf(v1, g1, g0);
                float f1 = fmaf(v1, g3, g2);
                res[q][r] = fmaf(v0, f1, f0);
            }
        }

        // coalesced float2 stores: 4 rows x (2 consecutive n per thread)
#pragma unroll
        for (int r = 0; r < BT; ++r) {
            float2 o; o.x = res[0][r]; o.y = res[1][r];
            *reinterpret_cast<float2*>(out + (size_t)(b0 + r) * NLUTS + n0) = o;
        }
    }
}

// ---------------- fallback (round-1 fused kernel, used only if ws too small) ----------------
#define F_TPB   256
#define F_NT    4
#define F_NPB   (F_TPB * F_NT)
#define F_NBLKN (NLUTS / F_NPB)
#define F_BTILE 16
#define F_GRID  (F_NBLKN * (BATCH / F_BTILE))

__global__ __launch_bounds__(F_TPB, 4)
void lut_fused(const float* __restrict__ x, const float* __restrict__ w,
               const float* __restrict__ wcomp, const int* __restrict__ indices,
               float* __restrict__ out)
{
    __shared__ float xsf[2][IDIM];
    int id = blockIdx.x;
    int swz = (id & 7) * (F_GRID / 8) + (id >> 3);
    int b_blk = swz / F_NBLKN, n_blk = swz % F_NBLKN;
    int t = threadIdx.x;
    int n0 = n_blk * F_NPB + t * F_NT;
    int b0 = b_blk * F_BTILE;
    int ix[F_NT][4];
#pragma unroll
    for (int i = 0; i < 4; ++i) {
        int4 v = *reinterpret_cast<const int4*>(indices + i * NLUTS + n0);
        ix[0][i] = v.x; ix[1][i] = v.y; ix[2][i] = v.z; ix[3][i] = v.w;
    }
    float a[F_NT][16];
#pragma unroll
    for (int q = 0; q < F_NT; ++q) {
        int n = n0 + q; float p[16];
#pragma unroll
        for (int k = 0; k < 4; ++k) {
            float4 wv = *reinterpret_cast<const float4*>(w     + (size_t)n * 16 + k * 4);
            float4 cv = *reinterpret_cast<const float4*>(wcomp + (size_t)n * 16 + k * 4);
            p[15-(4*k+0)] = 1.f/(1.f+__expf(cv.x-wv.x));
            p[15-(4*k+1)] = 1.f/(1.f+__expf(cv.y-wv.y));
            p[15-(4*k+2)] = 1.f/(1.f+__expf(cv.z-wv.z));
            p[15-(4*k+3)] = 1.f/(1.f+__expf(cv.w-wv.w));
        }
#pragma unroll
        for (int s = 8; s >= 1; s >>= 1)
#pragma unroll
            for (int m = 0; m < 16; ++m)
                if ((m & s) == 0) { float t0 = p[m]; p[m] = p[m+s]; p[m+s] = t0 - p[m+s]; }
#pragma unroll
        for (int m = 0; m < 16; ++m) a[q][m] = p[m];
    }
    {
        const float* xrow = x + (size_t)b0 * IDIM;
#pragma unroll
        for (int k = 0; k < 4; ++k)
            *reinterpret_cast<float4*>(&xsf[0][(k*F_TPB+t)*4]) =
                *reinterpret_cast<const float4*>(xrow + (k*F_TPB+t)*4);
    }
    __syncthreads();
    for (int bi = 0; bi < F_BTILE; ++bi) {
        int cur = bi & 1; bool more = (bi + 1 < F_BTILE);
        float4 r[4];
        if (more) {
            const float* xrow = x + (size_t)(b0+bi+1) * IDIM;
#pragma unroll
            for (int k = 0; k < 4; ++k)
                r[k] = *reinterpret_cast<const float4*>(xrow + (k*F_TPB+t)*4);
        }
        float res[F_NT];
#pragma unroll
        for (int q = 0; q < F_NT; ++q) {
            float v0 = xsf[cur][ix[q][0]], v1 = xsf[cur][ix[q][1]];
            float v2 = xsf[cur][ix[q][2]], v3 = xsf[cur][ix[q][3]];
            float h0 = fmaf(v3,a[q][1],a[q][0]),  h1 = fmaf(v3,a[q][3],a[q][2]);
            float h2 = fmaf(v3,a[q][5],a[q][4]),  h3 = fmaf(v3,a[q][7],a[q][6]);
            float h4 = fmaf(v3,a[q][9],a[q][8]),  h5 = fmaf(v3,a[q][11],a[q][10]);
            float h6 = fmaf(v3,a[q][13],a[q][12]),h7 = fmaf(v3,a[q][15],a[q][14]);
            float g0 = fmaf(v2,h1,h0), g1 = fmaf(v2,h3,h2);
            float g2 = fmaf(v2,h5,h4), g3 = fmaf(v2,h7,h6);
            res[q] = fmaf(v0, fmaf(v1,g3,g2), fmaf(v1,g1,g0));
        }
        float4 o; o.x=res[0]; o.y=res[1]; o.z=res[2]; o.w=res[3];
        *reinterpret_cast<float4*>(out + (size_t)(b0+bi)*NLUTS + n0) = o;
        if (more) {
            int nxt = cur ^ 1;
#pragma unroll
            for (int k = 0; k < 4; ++k)
                *reinterpret_cast<float4*>(&xsf[nxt][(k*F_TPB+t)*4]) = r[k];
        }
        __syncthreads();
    }
}

extern "C" void kernel_launch(void* const* d_in, const int* in_sizes, int n_in,
                              void* d_out, int out_size, void* d_ws, size_t ws_size,
                              hipStream_t stream) {
    const float* x   = (const float*)d_in[0];
    const float* w   = (const float*)d_in[1];
    const float* wc  = (const float*)d_in[2];
    const int*   idx = (const int*)d_in[3];
    float*       out = (float*)d_out;

    if (ws_size >= (size_t)NLUTS * 16 * sizeof(float)) {
        float* cf = (float*)d_ws;
        coeff_kernel<<<dim3(NLUTS / 256), dim3(256), 0, stream>>>(w, wc, cf);
        lut_main<<<dim3(GRID), dim3(TPB), 0, stream>>>(x, cf, idx, out);
    } else {
        lut_fused<<<dim3(F_GRID), dim3(F_TPB), 0, stream>>>(x, w, wc, idx, out);
    }
}

// Round 10
// 39.151 us; speedup vs baseline: 1.5737x; 1.3460x over previous
//
#include <hip/hip_runtime.h>
#include <hip/hip_fp16.h>
#include <stdint.h>

#define BATCH   1024
#define IDIM    4096
#define NLUTS   16384

// ---- main kernel geometry ----
#define TPB     1024
#define NT      2                    // n's per thread per chunk
#define NPB     (TPB * NT)           // 2048
#define CH      2                    // chunks per sweep
#define NSWEEP  (NPB * CH)           // 4096 n per block
#define NBLK_N  (NLUTS / NSWEEP)     // 4
#define BT      8                    // rows per LDS tile (fp16 -> b128 = 8 rows)
#define TILES   2
#define ROWS    (BT * TILES)         // 16 rows per block
#define NBLK_B  (BATCH / ROWS)       // 64
#define GRID    (NBLK_N * NBLK_B)    // 256 = 1 block per CU

// ---------------- coefficient pre-kernel ----------------
__global__ __launch_bounds__(256, 4)
void coeff_kernel(const float* __restrict__ w,
                  const float* __restrict__ wc,
                  float* __restrict__ cf)
{
    int n = blockIdx.x * 256 + threadIdx.x;   // grid = 64 x 256
    float p[16];
#pragma unroll
    for (int k = 0; k < 4; ++k) {
        float4 wv = *reinterpret_cast<const float4*>(w  + (size_t)n * 16 + 4 * k);
        float4 cv = *reinterpret_cast<const float4*>(wc + (size_t)n * 16 + 4 * k);
        p[15 - (4 * k + 0)] = 1.f / (1.f + __expf(cv.x - wv.x));
        p[15 - (4 * k + 1)] = 1.f / (1.f + __expf(cv.y - wv.y));
        p[15 - (4 * k + 2)] = 1.f / (1.f + __expf(cv.z - wv.z));
        p[15 - (4 * k + 3)] = 1.f / (1.f + __expf(cv.w - wv.w));
    }
#pragma unroll
    for (int s = 8; s >= 1; s >>= 1) {
#pragma unroll
        for (int m = 0; m < 16; ++m) {
            if ((m & s) == 0) { float t0 = p[m]; p[m] = p[m + s]; p[m + s] = t0 - p[m + s]; }
        }
    }
#pragma unroll
    for (int k = 0; k < 4; ++k) {
        float4 o; o.x = p[4*k]; o.y = p[4*k+1]; o.z = p[4*k+2]; o.w = p[4*k+3];
        *reinterpret_cast<float4*>(cf + (size_t)n * 16 + 4 * k) = o;
    }
}

// ---------------- main kernel ----------------
// Traffic-minimal tiling: block owns (4096 n) x (16 b-rows). cf read once per
// (block, chunk, tile) = BATCH/ROWS x 1MB = 128 MB total (R9: 256+), x staged
// NBLK_N=4x = 64 MB, out 64 MB. Long barrier-free sweeps between 4 barriers.
__global__ __launch_bounds__(TPB, 2)
void lut_main(const float* __restrict__ x,
              const float* __restrict__ cf,
              const int*   __restrict__ indices,
              float* __restrict__ out)
{
    // transposed fp16 tile: xt[col*8 + r] = x[brow+r][col]. 64 KB.
    __shared__ __half xt[IDIM * BT];

    // XCD swizzle: the 4 n-blocks sharing a b-range are consecutive on one
    // XCD -> staged x rows and cf slices L2-local (2 MB x per XCD).
    int id    = blockIdx.x;
    int xcd   = id & 7;
    int k     = id >> 3;               // 0..31
    int n_blk = k & (NBLK_N - 1);      // 0..3, fastest
    int b_blk = (k >> 2) * 8 + xcd;    // 0..63, bijective
    int t     = threadIdx.x;
    int b0    = b_blk * ROWS;
    int nbase = n_blk * NSWEEP;

    const char* xt_bytes = reinterpret_cast<const char*>(xt);

    // stage 8 rows: thread owns cols 4t..4t+3 (1024 threads x 4 cols = 4096).
    // Row-major float4 reads (fully coalesced), pack 8 rows/col -> uint4,
    // one ds_write_b128 per col.
    auto stage = [&](int g) {
        const float* xb = x + (size_t)(b0 + g * BT) * IDIM + 4 * t;
        float4 rr[BT];
#pragma unroll
        for (int r = 0; r < BT; ++r)
            rr[r] = *reinterpret_cast<const float4*>(xb + (size_t)r * IDIM);
#pragma unroll
        for (int j = 0; j < 4; ++j) {
            const float* f = reinterpret_cast<const float*>(&rr[0]);  // unrolled -> const idx
            float c0 = reinterpret_cast<const float*>(&rr[0])[j];
            float c1 = reinterpret_cast<const float*>(&rr[1])[j];
            float c2 = reinterpret_cast<const float*>(&rr[2])[j];
            float c3 = reinterpret_cast<const float*>(&rr[3])[j];
            float c4 = reinterpret_cast<const float*>(&rr[4])[j];
            float c5 = reinterpret_cast<const float*>(&rr[5])[j];
            float c6 = reinterpret_cast<const float*>(&rr[6])[j];
            float c7 = reinterpret_cast<const float*>(&rr[7])[j];
            (void)f;
            __half2 h01 = __floats2half2_rn(c0, c1);
            __half2 h23 = __floats2half2_rn(c2, c3);
            __half2 h45 = __floats2half2_rn(c4, c5);
            __half2 h67 = __floats2half2_rn(c6, c7);
            uint4 v;
            v.x = *reinterpret_cast<uint32_t*>(&h01);
            v.y = *reinterpret_cast<uint32_t*>(&h23);
            v.z = *reinterpret_cast<uint32_t*>(&h45);
            v.w = *reinterpret_cast<uint32_t*>(&h67);
            *reinterpret_cast<uint4*>(&xt[(size_t)(4 * t + j) * 8]) = v;
        }
    };

    // barrier-free sweep over this block's 4096 n for the staged 8 rows
    auto sweep = [&](int g) {
#pragma unroll 1
        for (int c = 0; c < CH; ++c) {
            int n0 = nbase + c * NPB + t * NT;

            uint32_t off[NT][4];
#pragma unroll
            for (int i = 0; i < 4; ++i) {
                int2 v = *reinterpret_cast<const int2*>(indices + i * NLUTS + n0);
                off[0][i] = (uint32_t)v.x * 16u;
                off[1][i] = (uint32_t)v.y * 16u;
            }

            float a[NT][16];
#pragma unroll
            for (int q = 0; q < NT; ++q) {
#pragma unroll
                for (int kk = 0; kk < 4; ++kk) {
                    float4 v = *reinterpret_cast<const float4*>(cf + (size_t)(n0 + q) * 16 + 4 * kk);
                    a[q][4*kk] = v.x; a[q][4*kk+1] = v.y; a[q][4*kk+2] = v.z; a[q][4*kk+3] = v.w;
                }
            }

            float res[NT][BT];
#pragma unroll
            for (int q = 0; q < NT; ++q) {
                uint4 gld[4];
#pragma unroll
                for (int i = 0; i < 4; ++i)
                    gld[i] = *reinterpret_cast<const uint4*>(xt_bytes + off[q][i]);

                float cc[4][BT];
#pragma unroll
                for (int i = 0; i < 4; ++i) {
                    __half2 h01 = *reinterpret_cast<__half2*>(&gld[i].x);
                    __half2 h23 = *reinterpret_cast<__half2*>(&gld[i].y);
                    __half2 h45 = *reinterpret_cast<__half2*>(&gld[i].z);
                    __half2 h67 = *reinterpret_cast<__half2*>(&gld[i].w);
                    float2 f01 = __half22float2(h01);
                    float2 f23 = __half22float2(h23);
                    float2 f45 = __half22float2(h45);
                    float2 f67 = __half22float2(h67);
                    cc[i][0] = f01.x; cc[i][1] = f01.y; cc[i][2] = f23.x; cc[i][3] = f23.y;
                    cc[i][4] = f45.x; cc[i][5] = f45.y; cc[i][6] = f67.x; cc[i][7] = f67.y;
                }
#pragma unroll
                for (int r = 0; r < BT; ++r) {
                    float v0 = cc[0][r], v1 = cc[1][r], v2 = cc[2][r], v3 = cc[3][r];
                    float h0 = fmaf(v3, a[q][1],  a[q][0]);
                    float h1 = fmaf(v3, a[q][3],  a[q][2]);
                    float h2 = fmaf(v3, a[q][5],  a[q][4]);
                    float h3 = fmaf(v3, a[q][7],  a[q][6]);
                    float h4 = fmaf(v3, a[q][9],  a[q][8]);
                    float h5 = fmaf(v3, a[q][11], a[q][10]);
                    float h6 = fmaf(v3, a[q][13], a[q][12]);
                    float h7 = fmaf(v3, a[q][15], a[q][14]);
                    float g0 = fmaf(v2, h1, h0);
                    float g1 = fmaf(v2, h3, h2);
                    float g2 = fmaf(v2, h5, h4);
                    float g3 = fmaf(v2, h7, h6);
                    float f0 = fmaf(v1, g1, g0);
                    float f1 = fmaf(v1, g3, g2);
                    res[q][r] = fmaf(v0, f1, f0);
                }
            }

            // coalesced float2 stores: 8 rows x (2 consecutive n per thread)
#pragma unroll
            for (int r = 0; r < BT; ++r) {
                float2 o; o.x = res[0][r]; o.y = res[1][r];
                *reinterpret_cast<float2*>(out + (size_t)(b0 + g * BT + r) * NLUTS + n0) = o;
            }
        }
    };

    stage(0);
    __syncthreads();
    sweep(0);
    __syncthreads();           // all reads of tile 0 done
    stage(1);
    __syncthreads();
    sweep(1);
}

// ---------------- fallback (round-1 fused kernel, used only if ws too small) ----------------
#define F_TPB   256
#define F_NT    4
#define F_NPB   (F_TPB * F_NT)
#define F_NBLKN (NLUTS / F_NPB)
#define F_BTILE 16
#define F_GRID  (F_NBLKN * (BATCH / F_BTILE))

__global__ __launch_bounds__(F_TPB, 4)
void lut_fused(const float* __restrict__ x, const float* __restrict__ w,
               const float* __restrict__ wcomp, const int* __restrict__ indices,
               float* __restrict__ out)
{
    __shared__ float xsf[2][IDIM];
    int id = blockIdx.x;
    int swz = (id & 7) * (F_GRID / 8) + (id >> 3);
    int b_blk = swz / F_NBLKN, n_blk = swz % F_NBLKN;
    int t = threadIdx.x;
    int n0 = n_blk * F_NPB + t * F_NT;
    int b0 = b_blk * F_BTILE;
    int ix[F_NT][4];
#pragma unroll
    for (int i = 0; i < 4; ++i) {
        int4 v = *reinterpret_cast<const int4*>(indices + i * NLUTS + n0);
        ix[0][i] = v.x; ix[1][i] = v.y; ix[2][i] = v.z; ix[3][i] = v.w;
    }
    float a[F_NT][16];
#pragma unroll
    for (int q = 0; q < F_NT; ++q) {
        int n = n0 + q; float p[16];
#pragma unroll
        for (int k = 0; k < 4; ++k) {
            float4 wv = *reinterpret_cast<const float4*>(w     + (size_t)n * 16 + k * 4);
            float4 cv = *reinterpret_cast<const float4*>(wcomp + (size_t)n * 16 + k * 4);
            p[15-(4*k+0)] = 1.f/(1.f+__expf(cv.x-wv.x));
            p[15-(4*k+1)] = 1.f/(1.f+__expf(cv.y-wv.y));
            p[15-(4*k+2)] = 1.f/(1.f+__expf(cv.z-wv.z));
            p[15-(4*k+3)] = 1.f/(1.f+__expf(cv.w-wv.w));
        }
#pragma unroll
        for (int s = 8; s >= 1; s >>= 1)
#pragma unroll
            for (int m = 0; m < 16; ++m)
                if ((m & s) == 0) { float t0 = p[m]; p[m] = p[m+s]; p[m+s] = t0 - p[m+s]; }
#pragma unroll
        for (int m = 0; m < 16; ++m) a[q][m] = p[m];
    }
    {
        const float* xrow = x + (size_t)b0 * IDIM;
#pragma unroll
        for (int k = 0; k < 4; ++k)
            *reinterpret_cast<float4*>(&xsf[0][(k*F_TPB+t)*4]) =
                *reinterpret_cast<const float4*>(xrow + (k*F_TPB+t)*4);
    }
    __syncthreads();
    for (int bi = 0; bi < F_BTILE; ++bi) {
        int cur = bi & 1; bool more = (bi + 1 < F_BTILE);
        float4 r[4];
        if (more) {
            const float* xrow = x + (size_t)(b0+bi+1) * IDIM;
#pragma unroll
            for (int k = 0; k < 4; ++k)
                r[k] = *reinterpret_cast<const float4*>(xrow + (k*F_TPB+t)*4);
        }
        float res[F_NT];
#pragma unroll
        for (int q = 0; q < F_NT; ++q) {
            float v0 = xsf[cur][ix[q][0]], v1 = xsf[cur][ix[q][1]];
            float v2 = xsf[cur][ix[q][2]], v3 = xsf[cur][ix[q][3]];
            float h0 = fmaf(v3,a[q][1],a[q][0]),  h1 = fmaf(v3,a[q][3],a[q][2]);
            float h2 = fmaf(v3,a[q][5],a[q][4]),  h3 = fmaf(v3,a[q][7],a[q][6]);
            float h4 = fmaf(v3,a[q][9],a[q][8]),  h5 = fmaf(v3,a[q][11],a[q][10]);
            float h6 = fmaf(v3,a[q][13],a[q][12]),h7 = fmaf(v3,a[q][15],a[q][14]);
            float g0 = fmaf(v2,h1,h0), g1 = fmaf(v2,h3,h2);
            float g2 = fmaf(v2,h5,h4), g3 = fmaf(v2,h7,h6);
            res[q] = fmaf(v0, fmaf(v1,g3,g2), fmaf(v1,g1,g0));
        }
        float4 o; o.x=res[0]; o.y=res[1]; o.z=res[2]; o.w=res[3];
        *reinterpret_cast<float4*>(out + (size_t)(b0+bi)*NLUTS + n0) = o;
        if (more) {
            int nxt = cur ^ 1;
#pragma unroll
            for (int k = 0; k < 4; ++k)
                *reinterpret_cast<float4*>(&xsf[nxt][(k*F_TPB+t)*4]) = r[k];
        }
        __syncthreads();
    }
}

extern "C" void kernel_launch(void* const* d_in, const int* in_sizes, int n_in,
                              void* d_out, int out_size, void* d_ws, size_t ws_size,
                              hipStream_t stream) {
    const float* x   = (const float*)d_in[0];
    const float* w   = (const float*)d_in[1];
    const float* wc  = (const float*)d_in[2];
    const int*   idx = (const int*)d_in[3];
    float*       out = (float*)d_out;

    if (ws_size >= (size_t)NLUTS * 16 * sizeof(float)) {
        float* cf = (float*)d_ws;
        coeff_kernel<<<dim3(NLUTS / 256), dim3(256), 0, stream>>>(w, wc, cf);
        lut_main<<<dim3(GRID), dim3(TPB), 0, stream>>>(x, cf, idx, out);
    } else {
        lut_fused<<<dim3(F_GRID), dim3(F_TPB), 0, stream>>>(x, w, wc, idx, out);
    }
}